// Round 5
// baseline (792.747 us; speedup 1.0000x reference)
//
#include <hip/hip_runtime.h>
#include <stdint.h>

// CaMoE block, MI355X gfx950. fp32 in/out. bf16/fp16 MFMA internals.
// Routing bids computed via exact decomposition:
//   h.w_j = [x.(g*w_j) + gated.(Wo@(g*w_j))]/sigma - (m/sigma)*sum(g*w_j) + sum(b*w_j)
// so only gemm_rv needs hp (2-term bf16 split); Wo GEMM is 1-pass fp16.
// Expert compute is routed (compaction + gathered GEMMs, early-exit blocks).
// R1: grid-packing — merged dual-expert z-launches, 128x64 tiles for N=1024.
// R3: launch-count reduction — batched transposes, zero-fold, 1 chunk-pass.
// R4: BK=64 thin GEMMs, expert_mid merges kgemm+t12b, vgemm3 merges V-GEMMs.
// R5: T1 XCD-aware block swizzle on the 4 big GEMMs — consecutive HW blocks
//     (round-robined over 8 XCD L2s) now map to contiguous work chunks, so
//     column-blocks sharing an A-row panel hit the same L2 (FETCH was 2.7x ideal).

#define N_TOK 8192
#define C_DIM 1024
#define H_DIM 4096

typedef unsigned short u16;
typedef __attribute__((ext_vector_type(8))) short short8;
typedef _Float16 half8 __attribute__((ext_vector_type(8)));
typedef __attribute__((ext_vector_type(4))) float floatx4;

__device__ __forceinline__ float b2f(u16 u) {
  union { unsigned u; float f; } v; v.u = ((unsigned)u) << 16; return v.f;
}
__device__ __forceinline__ u16 f2b(float f) {
  union { float f; unsigned u; } v; v.f = f;
  unsigned r = v.u + 0x7fffu + ((v.u >> 16) & 1u);  // RNE
  return (u16)(r >> 16);
}
__device__ __forceinline__ u16 f2h(float f) {
  union { _Float16 h; u16 u; } v; v.h = (_Float16)f; return v.u;
}
__device__ __forceinline__ float sigf(float x) { return 1.f / (1.f + __expf(-x)); }

typedef __attribute__((address_space(3))) unsigned int lds_uint;
typedef const __attribute__((address_space(1))) unsigned int glob_uint;
__device__ __forceinline__ void gld16(u16* lds, const u16* g) {
  __builtin_amdgcn_global_load_lds((glob_uint*)g, (lds_uint*)lds, 16, 0, 0);
}
__device__ __forceinline__ floatx4 mf(short8 a, short8 b, floatx4 c) {
  return __builtin_amdgcn_mfma_f32_16x16x32_bf16(a, b, c, 0, 0, 0);
}
__device__ __forceinline__ floatx4 mfh(half8 a, half8 b, floatx4 c) {
  return __builtin_amdgcn_mfma_f32_16x16x32_f16(a, b, c, 0, 0, 0);
}
// XCD-aware bijective block swizzle (T1). HW round-robins consecutive block
// ids over 8 XCDs; remap so XCD k runs a contiguous x-major chunk of work.
// Requires ntot % 8 == 0 (all uses: 1024/1536/3072). nx, ny powers of 2.
__device__ __forceinline__ int3 swz3(int nx, int ny, int ntot) {
  int lin = ((int)blockIdx.z * ny + (int)blockIdx.y) * nx + (int)blockIdx.x;
  const int q = ntot >> 3;
  lin = (lin & 7) * q + (lin >> 3);
  int3 r;
  r.x = lin % nx; r.y = (lin / nx) % ny; r.z = lin / (nx * ny);
  return r;
}
// stage two 16B chunks of a 128x32 tile (c0=tid, c1=tid+256)
__device__ __forceinline__ void stage2(u16* s, const u16* g, int K, int base,
                                       int c0, int c1, int k0) {
  gld16(s + c0 * 8, g + (size_t)(base + (c0 >> 2)) * K + k0 + (c0 & 3) * 8);
  gld16(s + c1 * 8, g + (size_t)(base + (c1 >> 2)) * K + k0 + (c1 & 3) * 8);
}
// stage one 16B chunk of a 64x32 tile (c=tid in 0..255)
__device__ __forceinline__ void stage1(u16* s, const u16* g, int K, int base,
                                       int c, int k0) {
  gld16(s + c * 8, g + (size_t)(base + (c >> 2)) * K + k0 + (c & 3) * 8);
}
template <typename V>
__device__ __forceinline__ void fragN(V* f, const u16* s, int wo, int fr, int fk, int n) {
  for (int i = 0; i < n; i++) f[i] = *(const V*)(s + (wo + i * 16 + fr) * 32 + fk);
}

// ============ hp dual GEMM: gated = sigmoid(A@Wr) * (A@Wv), tile 128x64 ======
// Writes gated hi/lo (bf16 pair, for exact routing dots) + g16 (fp16, Wo GEMM A).
__global__ __launch_bounds__(256) void gemm_rv(
    const u16* __restrict__ Ahi, const u16* __restrict__ Alo,
    const u16* __restrict__ Brh, const u16* __restrict__ Brl,
    const u16* __restrict__ Bvh, const u16* __restrict__ Bvl,
    int K, int NC, u16* __restrict__ Ghi, u16* __restrict__ Glo,
    u16* __restrict__ G16) {
  __shared__ __align__(16) u16 sAh[4096], sAl[4096];
  __shared__ __align__(16) u16 sRh[2048], sRl[2048], sVh[2048], sVl[2048];
  const int3 b = swz3(16, 64, 1024);
  const int tid = threadIdx.x, lane = tid & 63, wave = tid >> 6;
  const int rowbase = b.y * 128, colbase = b.x * 64;
  const int wm = (wave >> 1) * 64, wn = (wave & 1) * 32;
  floatx4 ar[4][2] = {}, av[4][2] = {};
  const int c0 = tid, c1 = tid + 256;
  for (int k0 = 0; k0 < K; k0 += 32) {
    __syncthreads();
    stage2(sAh, Ahi, K, rowbase, c0, c1, k0);
    stage2(sAl, Alo, K, rowbase, c0, c1, k0);
    stage1(sRh, Brh, K, colbase, c0, k0);
    stage1(sRl, Brl, K, colbase, c0, k0);
    stage1(sVh, Bvh, K, colbase, c0, k0);
    stage1(sVl, Bvl, K, colbase, c0, k0);
    __syncthreads();
    const int fr = lane & 15, fk = (lane >> 4) * 8;
    short8 ah[4], al[4], rh[2], rl[2], vh[2], vl[2];
    fragN(ah, sAh, wm, fr, fk, 4); fragN(al, sAl, wm, fr, fk, 4);
    fragN(rh, sRh, wn, fr, fk, 2); fragN(rl, sRl, wn, fr, fk, 2);
    fragN(vh, sVh, wn, fr, fk, 2); fragN(vl, sVl, wn, fr, fk, 2);
#pragma unroll
    for (int mi = 0; mi < 4; mi++)
#pragma unroll
      for (int ni = 0; ni < 2; ni++) {
        ar[mi][ni] = mf(ah[mi], rh[ni], ar[mi][ni]);
        ar[mi][ni] = mf(ah[mi], rl[ni], ar[mi][ni]);
        ar[mi][ni] = mf(al[mi], rh[ni], ar[mi][ni]);
        av[mi][ni] = mf(ah[mi], vh[ni], av[mi][ni]);
        av[mi][ni] = mf(ah[mi], vl[ni], av[mi][ni]);
        av[mi][ni] = mf(al[mi], vh[ni], av[mi][ni]);
      }
  }
  const int col0 = lane & 15, row0 = (lane >> 4) * 4;
#pragma unroll
  for (int mi = 0; mi < 4; mi++)
#pragma unroll
    for (int ni = 0; ni < 2; ni++)
#pragma unroll
      for (int r = 0; r < 4; r++) {
        const int row = rowbase + wm + mi * 16 + row0 + r;
        const int col = colbase + wn + ni * 16 + col0;
        const size_t idx = (size_t)row * NC + col;
        const float g = sigf(ar[mi][ni][r]) * av[mi][ni][r];
        const u16 h = f2b(g);
        Ghi[idx] = h;
        Glo[idx] = f2b(g - b2f(h));
        G16[idx] = f2h(g);
      }
}

// ============ fp16 GEMM: Xnew = Xin(fp32) + A@Wo, tile 128x64, BK=64 =========
__global__ __launch_bounds__(256) void gemm_wo_f16(
    const u16* __restrict__ A, const u16* __restrict__ BT, int K, int NC,
    const float* __restrict__ Xin, float* __restrict__ Xnew) {
  __shared__ __align__(16) u16 sA0[4096], sA1[4096], sB0[2048], sB1[2048];
  const int3 b = swz3(16, 64, 1024);
  const int tid = threadIdx.x, lane = tid & 63, wave = tid >> 6;
  const int rowbase = b.y * 128, colbase = b.x * 64;
  const int wm = (wave >> 1) * 64, wn = (wave & 1) * 32;
  floatx4 acc[4][2] = {};
  const int c0 = tid, c1 = tid + 256;
  for (int k0 = 0; k0 < K; k0 += 64) {
    __syncthreads();
    stage2(sA0, A, K, rowbase, c0, c1, k0);
    stage2(sA1, A, K, rowbase, c0, c1, k0 + 32);
    stage1(sB0, BT, K, colbase, c0, k0);
    stage1(sB1, BT, K, colbase, c0, k0 + 32);
    __syncthreads();
    const int fr = lane & 15, fk = (lane >> 4) * 8;
    half8 af[4], bf[2];
    fragN(af, sA0, wm, fr, fk, 4);
    fragN(bf, sB0, wn, fr, fk, 2);
#pragma unroll
    for (int mi = 0; mi < 4; mi++)
#pragma unroll
      for (int ni = 0; ni < 2; ni++)
        acc[mi][ni] = mfh(af[mi], bf[ni], acc[mi][ni]);
    fragN(af, sA1, wm, fr, fk, 4);
    fragN(bf, sB1, wn, fr, fk, 2);
#pragma unroll
    for (int mi = 0; mi < 4; mi++)
#pragma unroll
      for (int ni = 0; ni < 2; ni++)
        acc[mi][ni] = mfh(af[mi], bf[ni], acc[mi][ni]);
  }
  const int col0 = lane & 15, row0 = (lane >> 4) * 4;
#pragma unroll
  for (int mi = 0; mi < 4; mi++)
#pragma unroll
    for (int ni = 0; ni < 2; ni++)
#pragma unroll
      for (int r = 0; r < 4; r++) {
        const int row = rowbase + wm + mi * 16 + row0 + r;
        const int col = colbase + wn + ni * 16 + col0;
        const size_t idx = (size_t)row * NC + col;
        Xnew[idx] = Xin[idx] + acc[mi][ni][r];
      }
}

// ============ merged mid expert GEMMs, one launch ============================
// z=0,1: hr_e = relu(h@K_e)^2, tile 128x128, K=C (gathered rows).
// z=2:   tg = (h@W1)*sigmoid(xln@MT), tile 128x64 (x<16), K=C (gathered rows).
__global__ __launch_bounds__(256) void expert_mid(
    const u16* __restrict__ hb, const u16* __restrict__ xlnh,
    const int* __restrict__ idx,
    const u16* __restrict__ KT0p, const u16* __restrict__ KT1p,
    const u16* __restrict__ W1T, const u16* __restrict__ MTp,
    const int* __restrict__ counts, int base,
    u16* __restrict__ hr0, u16* __restrict__ hr1, u16* __restrict__ tg) {
  __shared__ __align__(16) u16 smem[12288];  // 24 KiB, partitioned per path
  const int3 b = swz3(32, 32, 3072);
  const int z = b.z;
  const int tid = threadIdx.x, lane = tid & 63, wave = tid >> 6;
  const int rowbase = b.y * 128;
  const int c0 = tid, c1 = tid + 256;
  const int fr = lane & 15, fk = (lane >> 4) * 8;
  const int col0 = lane & 15, row00 = (lane >> 4) * 4;
  if (z < 2) {
    const int cnt = counts[z] - base;
    if (rowbase >= cnt) return;
    const u16* BT = z ? KT1p : KT0p;
    const int* idxA = idx + z * N_TOK + base;
    u16* Cout = z ? hr1 : hr0;
    u16* sA = smem;          // 128x32
    u16* sB = smem + 4096;   // 128x32
    const int colbase = b.x * 128;
    const int wm = (wave >> 1) * 64, wn = (wave & 1) * 64;
    floatx4 acc[4][4] = {};
    const int g0 = idxA[rowbase + (c0 >> 2)], g1 = idxA[rowbase + (c1 >> 2)];
    const u16* pA0 = hb + (size_t)g0 * C_DIM + (c0 & 3) * 8;
    const u16* pA1 = hb + (size_t)g1 * C_DIM + (c1 & 3) * 8;
    const u16* pB0 = BT + (size_t)(colbase + (c0 >> 2)) * C_DIM + (c0 & 3) * 8;
    const u16* pB1 = BT + (size_t)(colbase + (c1 >> 2)) * C_DIM + (c1 & 3) * 8;
    for (int k0 = 0; k0 < C_DIM; k0 += 32) {
      __syncthreads();
      gld16(sA + c0 * 8, pA0 + k0);
      gld16(sA + c1 * 8, pA1 + k0);
      gld16(sB + c0 * 8, pB0 + k0);
      gld16(sB + c1 * 8, pB1 + k0);
      __syncthreads();
      short8 af[4], bf[4];
      fragN(af, sA, wm, fr, fk, 4);
      fragN(bf, sB, wn, fr, fk, 4);
#pragma unroll
      for (int mi = 0; mi < 4; mi++)
#pragma unroll
        for (int ni = 0; ni < 4; ni++)
          acc[mi][ni] = mf(af[mi], bf[ni], acc[mi][ni]);
    }
#pragma unroll
    for (int mi = 0; mi < 4; mi++)
#pragma unroll
      for (int ni = 0; ni < 4; ni++)
#pragma unroll
        for (int r = 0; r < 4; r++) {
          const int row = rowbase + wm + mi * 16 + row00 + r;
          const int col = colbase + wn + ni * 16 + col0;
          const float v = acc[mi][ni][r];
          const float t = v > 0.f ? v * v : 0.f;
          Cout[(size_t)row * H_DIM + col] = f2b(t);
        }
  } else {
    if (b.x >= 16) return;
    const int cnt = counts[2] - base;
    if (rowbase >= cnt) return;
    const int* idxA = idx + 2 * N_TOK + base;
    u16* s1 = smem;           // 128x32
    u16* s2 = smem + 4096;    // 128x32
    u16* sB1 = smem + 8192;   // 64x32
    u16* sB2 = smem + 10240;  // 64x32
    const int colbase = b.x * 64;
    const int wm = (wave >> 1) * 64, wn = (wave & 1) * 32;
    floatx4 a1[4][2] = {}, a2[4][2] = {};
    const int g0 = idxA[rowbase + (c0 >> 2)], g1 = idxA[rowbase + (c1 >> 2)];
    const u16* p10 = hb + (size_t)g0 * C_DIM + (c0 & 3) * 8;
    const u16* p11 = hb + (size_t)g1 * C_DIM + (c1 & 3) * 8;
    const u16* p20 = xlnh + (size_t)g0 * C_DIM + (c0 & 3) * 8;
    const u16* p21 = xlnh + (size_t)g1 * C_DIM + (c1 & 3) * 8;
    for (int k0 = 0; k0 < C_DIM; k0 += 32) {
      __syncthreads();
      gld16(s1 + c0 * 8, p10 + k0);
      gld16(s1 + c1 * 8, p11 + k0);
      gld16(s2 + c0 * 8, p20 + k0);
      gld16(s2 + c1 * 8, p21 + k0);
      stage1(sB1, W1T, C_DIM, colbase, c0, k0);
      stage1(sB2, MTp, C_DIM, colbase, c0, k0);
      __syncthreads();
      short8 f1[4], f2[4], b1[2], b2[2];
      fragN(f1, s1, wm, fr, fk, 4); fragN(f2, s2, wm, fr, fk, 4);
      fragN(b1, sB1, wn, fr, fk, 2); fragN(b2, sB2, wn, fr, fk, 2);
#pragma unroll
      for (int mi = 0; mi < 4; mi++)
#pragma unroll
        for (int ni = 0; ni < 2; ni++) {
          a1[mi][ni] = mf(f1[mi], b1[ni], a1[mi][ni]);
          a2[mi][ni] = mf(f2[mi], b2[ni], a2[mi][ni]);
        }
    }
#pragma unroll
    for (int mi = 0; mi < 4; mi++)
#pragma unroll
      for (int ni = 0; ni < 2; ni++)
#pragma unroll
        for (int r = 0; r < 4; r++) {
          const int row = rowbase + wm + mi * 16 + row00 + r;
          const int col = colbase + wn + ni * 16 + col0;
          tg[(size_t)(base + row) * C_DIM + col] =
              f2b(a1[mi][ni][r] * sigf(a2[mi][ni][r]));
        }
  }
}

// ============ merged out GEMMs: out = x_new + (A@B)*scale, 128x64, BK=64 =====
// z=0,1: A=hr_e (chunk-local rows), B=V_e, K=H.  z=2: A=tg (base+row), B=W3, K=C.
__global__ __launch_bounds__(256) void vgemm3(
    const u16* __restrict__ hr0, const u16* __restrict__ hr1,
    const u16* __restrict__ tg,
    const u16* __restrict__ VT0p, const u16* __restrict__ VT1p,
    const u16* __restrict__ W3T,
    const int* __restrict__ counts, int base, const int* __restrict__ idx,
    const float* __restrict__ x_new, const float* __restrict__ scalep,
    float* __restrict__ out) {
  const int3 b = swz3(16, 32, 1536);
  const int z = b.z;
  const int cnt = counts[z] - base;
  const int rowbase = b.y * 128;
  if (rowbase >= cnt) return;
  const u16* A; const u16* BT; int K; int arow;
  if (z == 0)      { A = hr0; BT = VT0p; K = H_DIM; arow = rowbase; }
  else if (z == 1) { A = hr1; BT = VT1p; K = H_DIM; arow = rowbase; }
  else             { A = tg;  BT = W3T;  K = C_DIM; arow = base + rowbase; }
  const int* idxO = idx + z * N_TOK + base;
  __shared__ __align__(16) u16 sA0[4096], sA1[4096], sB0[2048], sB1[2048];
  const int tid = threadIdx.x, lane = tid & 63, wave = tid >> 6;
  const int colbase = b.x * 64;
  const int wm = (wave >> 1) * 64, wn = (wave & 1) * 32;
  floatx4 acc[4][2] = {};
  const int c0 = tid, c1 = tid + 256;
  for (int k0 = 0; k0 < K; k0 += 64) {
    __syncthreads();
    stage2(sA0, A, K, arow, c0, c1, k0);
    stage2(sA1, A, K, arow, c0, c1, k0 + 32);
    stage1(sB0, BT, K, colbase, c0, k0);
    stage1(sB1, BT, K, colbase, c0, k0 + 32);
    __syncthreads();
    const int fr = lane & 15, fk = (lane >> 4) * 8;
    short8 af[4], bf[2];
    fragN(af, sA0, wm, fr, fk, 4);
    fragN(bf, sB0, wn, fr, fk, 2);
#pragma unroll
    for (int mi = 0; mi < 4; mi++)
#pragma unroll
      for (int ni = 0; ni < 2; ni++)
        acc[mi][ni] = mf(af[mi], bf[ni], acc[mi][ni]);
    fragN(af, sA1, wm, fr, fk, 4);
    fragN(bf, sB1, wn, fr, fk, 2);
#pragma unroll
    for (int mi = 0; mi < 4; mi++)
#pragma unroll
      for (int ni = 0; ni < 2; ni++)
        acc[mi][ni] = mf(af[mi], bf[ni], acc[mi][ni]);
  }
  const int col0 = lane & 15, row0 = (lane >> 4) * 4;
#pragma unroll
  for (int mi = 0; mi < 4; mi++)
#pragma unroll
    for (int ni = 0; ni < 2; ni++)
#pragma unroll
      for (int r = 0; r < 4; r++) {
        const int row = rowbase + wm + mi * 16 + row0 + r;
        if (row < cnt) {
          const int col = colbase + wn + ni * 16 + col0;
          const int g = idxO[row];
          const size_t o = (size_t)g * C_DIM + col;
          out[o] = x_new[o] + acc[mi][ni][r] * scalep[g];
        }
      }
}

// ============ plain bf16 GEMM, tile 128x128 (MT = W2T @ Wsb prep) ============
template <int EPI>
__global__ __launch_bounds__(256) void ggemm(
    const u16* __restrict__ A, const int* __restrict__ idxA,
    const u16* __restrict__ BT, int K, int NC,
    const int* __restrict__ cntp, int base,
    u16* __restrict__ Cout,
    const float* __restrict__ x_new, const float* __restrict__ scalep,
    const int* __restrict__ idxO, float* __restrict__ out) {
  const int cnt = cntp ? (*cntp - base) : (int)(gridDim.y * 128);
  if ((int)blockIdx.y * 128 >= cnt) return;
  __shared__ __align__(16) u16 sA[4096], sB[4096];
  const int tid = threadIdx.x, lane = tid & 63, wave = tid >> 6;
  const int rowbase = blockIdx.y * 128, colbase = blockIdx.x * 128;
  const int wm = (wave >> 1) * 64, wn = (wave & 1) * 64;
  floatx4 acc[4][4] = {};
  const int c0 = tid, c1 = tid + 256;
  const int r0 = rowbase + (c0 >> 2), r1 = rowbase + (c1 >> 2);
  const int g0 = idxA ? idxA[base + r0] : r0;
  const int g1 = idxA ? idxA[base + r1] : r1;
  const u16* pA0 = A + (size_t)g0 * K + (c0 & 3) * 8;
  const u16* pA1 = A + (size_t)g1 * K + (c1 & 3) * 8;
  const u16* pB0 = BT + (size_t)(colbase + (c0 >> 2)) * K + (c0 & 3) * 8;
  const u16* pB1 = BT + (size_t)(colbase + (c1 >> 2)) * K + (c1 & 3) * 8;
  for (int k0 = 0; k0 < K; k0 += 32) {
    __syncthreads();
    gld16(sA + c0 * 8, pA0 + k0);
    gld16(sA + c1 * 8, pA1 + k0);
    gld16(sB + c0 * 8, pB0 + k0);
    gld16(sB + c1 * 8, pB1 + k0);
    __syncthreads();
    const int fr = lane & 15, fk = (lane >> 4) * 8;
    short8 af[4], bf[4];
    fragN(af, sA, wm, fr, fk, 4);
    fragN(bf, sB, wn, fr, fk, 4);
#pragma unroll
    for (int mi = 0; mi < 4; mi++)
#pragma unroll
      for (int ni = 0; ni < 4; ni++)
        acc[mi][ni] = mf(af[mi], bf[ni], acc[mi][ni]);
  }
  const int col0 = lane & 15, row00 = (lane >> 4) * 4;
#pragma unroll
  for (int mi = 0; mi < 4; mi++)
#pragma unroll
    for (int ni = 0; ni < 4; ni++)
#pragma unroll
      for (int r = 0; r < 4; r++) {
        const int row = rowbase + wm + mi * 16 + row00 + r;
        const int col = colbase + wn + ni * 16 + col0;
        const float v = acc[mi][ni][r];
        if constexpr (EPI == 0) {
          Cout[(size_t)row * NC + col] = f2b(v);
        } else if constexpr (EPI == 2) {
          const float t = v > 0.f ? v * v : 0.f;
          Cout[(size_t)row * NC + col] = f2b(t);
        } else {
          if (row < cnt) {
            const int g = idxO[base + row];
            const size_t o = (size_t)g * NC + col;
            out[o] = x_new[o] + v * scalep[g];
          }
        }
      }
}

// ============ batched C×C weight transposes (z picks matrix) =================
// z: 0=Wr(bf16 hi/lo) 1=Wv(bf16 hi/lo) 2=Wo(fp16) 3=W1 4=W2 5=W3 (bf16 hi)
struct CCBatchArgs {
  const float *Wr, *Wv, *Wo, *W1, *W2, *W3;
  u16 *WrTh, *WrTl, *WvTh, *WvTl, *WoT16, *W1T, *W2T, *W3T;
};
__global__ __launch_bounds__(256) void transpose_cc_batch(CCBatchArgs a) {
  __shared__ float tile[32][33];
  const int z = blockIdx.z;
  const float* in; u16* oh; u16* ol = nullptr; int mode;  // 0 hi,1 hi+lo,2 f16
  switch (z) {
    case 0: in = a.Wr; oh = a.WrTh; ol = a.WrTl; mode = 1; break;
    case 1: in = a.Wv; oh = a.WvTh; ol = a.WvTl; mode = 1; break;
    case 2: in = a.Wo; oh = a.WoT16; mode = 2; break;
    case 3: in = a.W1; oh = a.W1T; mode = 0; break;
    case 4: in = a.W2; oh = a.W2T; mode = 0; break;
    default: in = a.W3; oh = a.W3T; mode = 0; break;
  }
  const int tx = threadIdx.x & 31, ty = threadIdx.x >> 5;
  const int bx = blockIdx.x * 32, by = blockIdx.y * 32;
#pragma unroll
  for (int i = 0; i < 32; i += 8)
    tile[ty + i][tx] = in[(size_t)(by + ty + i) * C_DIM + bx + tx];
  __syncthreads();
#pragma unroll
  for (int i = 0; i < 32; i += 8) {
    const float v = tile[tx][ty + i];
    const size_t o = (size_t)(bx + ty + i) * C_DIM + by + tx;
    if (mode == 2) {
      oh[o] = f2h(v);
    } else {
      const u16 h = f2b(v);
      oh[o] = h;
      if (mode == 1) ol[o] = f2b(v - b2f(h));
    }
  }
}

// ============ batched K/V expert transposes (z picks expert) =================
__global__ __launch_bounds__(256) void transpose_kv(
    const float* __restrict__ in, u16* __restrict__ o0, u16* __restrict__ o1,
    int R, int Cc) {
  __shared__ float tile[32][33];
  const float* ip = in + (size_t)blockIdx.z * R * Cc;
  u16* oh = blockIdx.z ? o1 : o0;
  const int tx = threadIdx.x & 31, ty = threadIdx.x >> 5;
  const int bx = blockIdx.x * 32, by = blockIdx.y * 32;
#pragma unroll
  for (int i = 0; i < 32; i += 8)
    tile[ty + i][tx] = ip[(size_t)(by + ty + i) * Cc + bx + tx];
  __syncthreads();
#pragma unroll
  for (int i = 0; i < 32; i += 8)
    oh[(size_t)(bx + ty + i) * R + by + tx] = f2b(tile[tx][ty + i]);
}

// ============ fp32 -> bf16 straight cast =====================================
__global__ __launch_bounds__(256) void cast_kernel(const float* __restrict__ in,
                                                   u16* __restrict__ o, int n) {
  const int i = blockIdx.x * 256 + threadIdx.x;
  if (i < n) o[i] = f2b(in[i]);
}

// ============ LayerNorm fp32 -> bf16 hi + lo (LN1) ===========================
__global__ __launch_bounds__(256) void ln_kernel(
    const float* __restrict__ x, const float* __restrict__ w,
    const float* __restrict__ b, u16* __restrict__ oh, u16* __restrict__ ol) {
  const int row = blockIdx.x, tid = threadIdx.x;
  const float* xr = x + (size_t)row * C_DIM;
  float vals[4], s = 0.f, ss = 0.f;
#pragma unroll
  for (int i = 0; i < 4; i++) {
    const float t = xr[tid + i * 256];
    vals[i] = t; s += t; ss += t * t;
  }
  for (int off = 32; off; off >>= 1) {
    s += __shfl_xor(s, off, 64);
    ss += __shfl_xor(ss, off, 64);
  }
  __shared__ float red[8];
  const int lane = tid & 63, wave = tid >> 6;
  if (lane == 0) { red[wave] = s; red[4 + wave] = ss; }
  __syncthreads();
  const float S = red[0] + red[1] + red[2] + red[3];
  const float SS = red[4] + red[5] + red[6] + red[7];
  const float mean = S * (1.f / C_DIM);
  const float var = SS * (1.f / C_DIM) - mean * mean;
  const float inv = rsqrtf(var + 1e-5f);
#pragma unroll
  for (int i = 0; i < 4; i++) {
    const int c = tid + i * 256;
    const float y = (vals[i] - mean) * inv * w[c] + b[c];
    const u16 h = f2b(y);
    oh[(size_t)row * C_DIM + c] = h;
    ol[(size_t)row * C_DIM + c] = f2b(y - b2f(h));
  }
}

// ============ prep: p_j = ln2w * w_j ; g_j = sum(p_j) ; b_j = sum(ln2b*w_j) ==
__global__ __launch_bounds__(256) void prep_vec(
    const float* __restrict__ ln2w, const float* __restrict__ ln2b,
    const float* __restrict__ conf_rwkv, const float* __restrict__ conf_trans,
    const float* __restrict__ w_diff, const float* __restrict__ W_aff,
    float* __restrict__ p, float* __restrict__ sg, float* __restrict__ sb) {
  const int j = blockIdx.x, tid = threadIdx.x;
  float gs = 0.f, bs = 0.f;
#pragma unroll
  for (int i = 0; i < 4; i++) {
    const int c = tid + i * 256;
    float wv;
    if (j == 0) wv = conf_rwkv[c];
    else if (j == 1) wv = conf_rwkv[C_DIM + c];
    else if (j == 2) wv = conf_trans[c];
    else if (j == 3) wv = w_diff[c];
    else wv = W_aff[c * 3 + (j - 4)];
    const float pv = ln2w[c] * wv;
    p[j * C_DIM + c] = pv;
    gs += pv;
    bs += ln2b[c] * wv;
  }
  for (int off = 32; off; off >>= 1) {
    gs += __shfl_xor(gs, off, 64);
    bs += __shfl_xor(bs, off, 64);
  }
  __shared__ float red[8];
  const int lane = tid & 63, wave = tid >> 6;
  if (lane == 0) { red[wave] = gs; red[4 + wave] = bs; }
  __syncthreads();
  if (tid == 0) {
    sg[j] = red[0] + red[1] + red[2] + red[3];
    sb[j] = red[4] + red[5] + red[6] + red[7];
  }
}

// ============ u_j = Wo @ p_j  (fp32 GEMV, one wave per output element) =======
__global__ __launch_bounds__(256) void ugemv(
    const float* __restrict__ Wo, const float* __restrict__ p,
    float* __restrict__ u) {
  const int o = blockIdx.x * 4 + (threadIdx.x >> 6);
  const int lane = threadIdx.x & 63;
  const int j = o >> 10, k = o & 1023;
  float s = 0.f;
#pragma unroll
  for (int i = 0; i < 16; i++) {
    const int c = lane + i * 64;
    s += Wo[(size_t)k * C_DIM + c] * p[j * C_DIM + c];
  }
  for (int off = 32; off; off >>= 1) s += __shfl_xor(s, off, 64);
  if (lane == 0) u[o] = s;
}

// ============ routing: exact bids via decomposition; emits h (bf16) ==========
// Also zeroes idx+counts (pz) in its first blocks, replacing zero_kernel.
__global__ __launch_bounds__(256) void route_kernel(
    const float* __restrict__ x, const float* __restrict__ xn,
    const u16* __restrict__ ghi, const u16* __restrict__ glo,
    const float* __restrict__ p, const float* __restrict__ u,
    const float* __restrict__ sg, const float* __restrict__ sb,
    const float* __restrict__ ln2w, const float* __restrict__ ln2b,
    const float* __restrict__ capital,
    int* __restrict__ winner, float* __restrict__ scale, u16* __restrict__ oh,
    int* __restrict__ pz, int nz) {
  {
    const int i = blockIdx.x * 256 + threadIdx.x;
    if (i < nz) pz[i] = 0;
  }
  const int token = blockIdx.x * 4 + (threadIdx.x >> 6);
  const int lane = threadIdx.x & 63;
  const float* xnr = xn + (size_t)token * C_DIM;
  float xv[16], s = 0.f, ss = 0.f;
#pragma unroll
  for (int i = 0; i < 16; i++) {
    const float t = xnr[lane + i * 64];
    xv[i] = t; s += t; ss += t * t;
  }
  for (int off = 32; off; off >>= 1) {
    s += __shfl_xor(s, off, 64);
    ss += __shfl_xor(ss, off, 64);
  }
  const float mean = s * (1.f / C_DIM);
  const float var = ss * (1.f / C_DIM) - mean * mean;
  const float inv = rsqrtf(var + 1e-5f);
  float acc[7] = {};
#pragma unroll
  for (int i = 0; i < 16; i++) {
    const int c = lane + i * 64;
    // h output for experts
    oh[(size_t)token * C_DIM + c] = f2b((xv[i] - mean) * inv * ln2w[c] + ln2b[c]);
    const float xc = x[(size_t)token * C_DIM + c];
    const float gc = b2f(ghi[(size_t)token * C_DIM + c]) +
                     b2f(glo[(size_t)token * C_DIM + c]);
#pragma unroll
    for (int j = 0; j < 7; j++)
      acc[j] += xc * p[j * C_DIM + c] + gc * u[j * C_DIM + c];
  }
  for (int off = 32; off; off >>= 1)
#pragma unroll
    for (int j = 0; j < 7; j++) acc[j] += __shfl_xor(acc[j], off, 64);
  if (lane == 0) {
    float hw[7];
#pragma unroll
    for (int j = 0; j < 7; j++) hw[j] = acc[j] * inv - mean * inv * sg[j] + sb[j];
    const float conf[3] = {1.f / (1.f + expf(-hw[0])), 1.f / (1.f + expf(-hw[1])),
                           1.f / (1.f + expf(-hw[2]))};
    const float diff = 1.f / (1.f + expf(-hw[3]));
    int best = 0; float bb = -1e30f;
#pragma unroll
    for (int e = 0; e < 3; e++) {
      const float bid = conf[e] * capital[e] * diff + hw[4 + e];
      if (bid > bb) { bb = bid; best = e; }  // first-max ties = jnp.argmax
    }
    winner[token] = best;
    scale[token] = conf[best] / (conf[best] + 1e-6f);
  }
}

// ============ compaction =====================================================
__global__ __launch_bounds__(256) void compact_kernel(
    const int* __restrict__ winner, int* __restrict__ idx, int* __restrict__ counts) {
  const int t = blockIdx.x * 256 + threadIdx.x;
  const int w = winner[t];
  const int pos = atomicAdd(counts + w, 1);
  idx[w * N_TOK + pos] = t;
}

extern "C" void kernel_launch(void* const* d_in, const int* in_sizes, int n_in,
                              void* d_out, int out_size, void* d_ws, size_t ws_size,
                              hipStream_t stream) {
  const float* x = (const float*)d_in[0];
  const float* capital = (const float*)d_in[2];
  const float* ln1w = (const float*)d_in[3];
  const float* ln1b = (const float*)d_in[4];
  const float* ln2w = (const float*)d_in[5];
  const float* ln2b = (const float*)d_in[6];
  const float* Wr = (const float*)d_in[7];
  const float* Wv = (const float*)d_in[8];
  const float* Wo = (const float*)d_in[9];
  const float* Wsm = (const float*)d_in[10];
  const float* Krwkv = (const float*)d_in[11];   // (2, C, H)
  const float* Vrwkv = (const float*)d_in[12];   // (2, H, C)
  const float* conf_rwkv = (const float*)d_in[13];
  const float* W1 = (const float*)d_in[14];
  const float* W2 = (const float*)d_in[15];
  const float* W3 = (const float*)d_in[16];
  const float* conf_trans = (const float*)d_in[17];
  const float* w_diff = (const float*)d_in[18];
  const float* W_aff = (const float*)d_in[19];
  float* out = (float*)d_out;

  char* ws = (char*)d_ws;
  size_t off = 0;
  auto alloc = [&](size_t bytes) -> char* {
    char* pp = ws + off;
    off += (bytes + 255) & ~(size_t)255;
    return pp;
  };
  const size_t CC = (size_t)C_DIM * C_DIM * 2;   // 2 MiB
  const size_t CH = (size_t)C_DIM * H_DIM * 2;   // 8 MiB
  const size_t NCb = (size_t)N_TOK * C_DIM * 2;  // 16 MiB
  u16* WrTh = (u16*)alloc(CC); u16* WrTl = (u16*)alloc(CC);
  u16* WvTh = (u16*)alloc(CC); u16* WvTl = (u16*)alloc(CC);
  u16* WoT16 = (u16*)alloc(CC);
  u16* W1T = (u16*)alloc(CC);
  u16* W2T = (u16*)alloc(CC);
  u16* W3T = (u16*)alloc(CC);
  u16* Wsb = (u16*)alloc(CC);
  u16* MT  = (u16*)alloc(CC);   // (Ws@W2)^T
  u16* KT0 = (u16*)alloc(CH);
  u16* VT0 = (u16*)alloc(CH);
  u16* KT1 = (u16*)alloc(CH);
  u16* VT1 = (u16*)alloc(CH);
  u16* xlnh = (u16*)alloc(NCb);   // LN1 hi (live through expert_mid)
  u16* xlnl = (u16*)alloc(NCb);   // LN1 lo; reused as hb (h bf16) after rv
  u16* ghi = (u16*)alloc(NCb);    // gated hi; reused as tg after route
  u16* glo = (u16*)alloc(NCb);    // gated lo; +g16 reused as hr0 after route
  u16* g16 = (u16*)alloc(NCb);    // gated fp16 (Wo GEMM A); part of hr0 after
  float* x_new = (float*)alloc((size_t)N_TOK * C_DIM * 4);  // 32 MiB
  u16* hr1 = (u16*)alloc((size_t)4096 * H_DIM * 2);         // 32 MiB: e1 chunk
  u16* hr0 = glo;  // glo(16MiB)+g16(16MiB) contiguous -> e0 chunk [4096][H]
  int* idx = (int*)alloc(3 * N_TOK * 4);   // contiguous with counts (both 256-aligned)
  int* counts = (int*)alloc(256);
  int* winner = (int*)alloc(N_TOK * 4);
  float* scalep = (float*)alloc(N_TOK * 4);
  float* pvec = (float*)alloc(7 * C_DIM * 4);
  float* uvec = (float*)alloc(7 * C_DIM * 4);
  float* sgv = (float*)alloc(256);
  float* sbv = (float*)alloc(256);

  const dim3 blk(256);
  // batched weight prep: 6 CxC transposes in one launch, K/V pairs in one each
  CCBatchArgs ta = {Wr, Wv, Wo, W1, W2, W3,
                    WrTh, WrTl, WvTh, WvTl, WoT16, W1T, W2T, W3T};
  transpose_cc_batch<<<dim3(32, 32, 6), blk, 0, stream>>>(ta);
  transpose_kv<<<dim3(H_DIM / 32, C_DIM / 32, 2), blk, 0, stream>>>(
      Krwkv, KT0, KT1, C_DIM, H_DIM);
  transpose_kv<<<dim3(C_DIM / 32, H_DIM / 32, 2), blk, 0, stream>>>(
      Vrwkv, VT0, VT1, H_DIM, C_DIM);
  cast_kernel<<<(C_DIM * C_DIM) / 256, blk, 0, stream>>>(Wsm, Wsb, C_DIM * C_DIM);
  // MT = W2T @ Wsb  -> (Ws@W2)^T
  ggemm<0><<<dim3(8, 8), blk, 0, stream>>>(W2T, nullptr, Wsb, C_DIM, C_DIM,
      nullptr, 0, MT, nullptr, nullptr, nullptr, nullptr);
  // routing-vector prep
  prep_vec<<<7, blk, 0, stream>>>(ln2w, ln2b, conf_rwkv, conf_trans, w_diff,
                                  W_aff, pvec, sgv, sbv);
  ugemv<<<7 * C_DIM / 4, blk, 0, stream>>>(Wo, pvec, uvec);

  // LN1 (split)
  ln_kernel<<<N_TOK, blk, 0, stream>>>(x, ln1w, ln1b, xlnh, xlnl);

  // gated = sigmoid(xln@Wr) * (xln@Wv)  (hi/lo + fp16), tile 128x64
  gemm_rv<<<dim3(C_DIM / 64, N_TOK / 128), blk, 0, stream>>>(
      xlnh, xlnl, WrTh, WrTl, WvTh, WvTl, C_DIM, C_DIM, ghi, glo, g16);
  // x_new = x + gated @ Wo (fp16 single pass), tile 128x64 BK=64
  gemm_wo_f16<<<dim3(C_DIM / 64, N_TOK / 128), blk, 0, stream>>>(
      g16, WoT16, C_DIM, C_DIM, x, x_new);
  // routing: exact bids + h (bf16 into xlnl-reuse = hb) + zero idx/counts
  u16* hb = xlnl;
  route_kernel<<<N_TOK / 4, blk, 0, stream>>>(x, x_new, ghi, glo, pvec, uvec,
      sgv, sbv, ln2w, ln2b, capital, winner, scalep, hb, idx, 3 * N_TOK + 64);
  compact_kernel<<<N_TOK / 256, blk, 0, stream>>>(winner, idx, counts);

  // ---- all experts, chunked 4096 rows (chunk 1 only on overflow) ----
  u16* tg = ghi;  // ghi free after route
  for (int c = 0; c < 2; c++) {
    const int base = c * 4096;
    // z=0,1: hr_e = relu(h@K_e)^2 (128x128); z=2: tg = (h@W1)*sig(xln@MT)
    expert_mid<<<dim3(H_DIM / 128, 32, 3), blk, 0, stream>>>(
        hb, xlnh, idx, KT0, KT1, W1T, MT, counts, base, hr0, hr1, tg);
    // z=0,1: out = x_new + (hr_e@V_e)*scale; z=2: out = x_new + (tg@W3)*scale
    vgemm3<<<dim3(C_DIM / 64, 32, 3), blk, 0, stream>>>(
        hr0, hr1, tg, VT0, VT1, W3T, counts, base, idx, x_new, scalep, out);
  }
}

// Round 6
// 695.836 us; speedup vs baseline: 1.1393x; 1.1393x over previous
//
#include <hip/hip_runtime.h>
#include <stdint.h>

// CaMoE block, MI355X gfx950. fp32 in/out. bf16/fp16 MFMA internals.
// Routing bids computed via exact decomposition:
//   h.w_j = [x.(g*w_j) + gated.(Wo@(g*w_j))]/sigma - (m/sigma)*sum(g*w_j) + sum(b*w_j)
// so only gemm_rv needs hp (2-term bf16 split); Wo GEMM is 1-pass fp16.
// Expert compute is routed (compaction + gathered GEMMs, early-exit blocks).
// R1: grid-packing — merged dual-expert z-launches, 128x64 tiles for N=1024.
// R3: launch-count reduction — batched transposes, zero-fold, 1 chunk-pass.
// R4: BK=64 thin GEMMs, expert_mid merges kgemm+t12b, vgemm3 merges V-GEMMs.
// R5: XCD swizzle v1 (contiguous chunks) — fixed FETCH 271->110MB but broke
//     XCD load balance (cheap z=2 + dead-tail blocks clustered) -> regressed.
// R6: swzr — x-blocks of one row-panel stay on one XCD (keeps L2 locality),
//     rows round-robin across XCDs (restores balance).

#define N_TOK 8192
#define C_DIM 1024
#define H_DIM 4096

typedef unsigned short u16;
typedef __attribute__((ext_vector_type(8))) short short8;
typedef _Float16 half8 __attribute__((ext_vector_type(8)));
typedef __attribute__((ext_vector_type(4))) float floatx4;

__device__ __forceinline__ float b2f(u16 u) {
  union { unsigned u; float f; } v; v.u = ((unsigned)u) << 16; return v.f;
}
__device__ __forceinline__ u16 f2b(float f) {
  union { float f; unsigned u; } v; v.f = f;
  unsigned r = v.u + 0x7fffu + ((v.u >> 16) & 1u);  // RNE
  return (u16)(r >> 16);
}
__device__ __forceinline__ u16 f2h(float f) {
  union { _Float16 h; u16 u; } v; v.h = (_Float16)f; return v.u;
}
__device__ __forceinline__ float sigf(float x) { return 1.f / (1.f + __expf(-x)); }

typedef __attribute__((address_space(3))) unsigned int lds_uint;
typedef const __attribute__((address_space(1))) unsigned int glob_uint;
__device__ __forceinline__ void gld16(u16* lds, const u16* g) {
  __builtin_amdgcn_global_load_lds((glob_uint*)g, (lds_uint*)lds, 16, 0, 0);
}
__device__ __forceinline__ floatx4 mf(short8 a, short8 b, floatx4 c) {
  return __builtin_amdgcn_mfma_f32_16x16x32_bf16(a, b, c, 0, 0, 0);
}
__device__ __forceinline__ floatx4 mfh(half8 a, half8 b, floatx4 c) {
  return __builtin_amdgcn_mfma_f32_16x16x32_f16(a, b, c, 0, 0, 0);
}
// XCD-aware row-preserving swizzle (T1, balanced). HW round-robins block ids
// over 8 XCDs (xcd = lin&7). Within an XCD the arrival sequence s=lin>>3 is
// split as x = s%nx (so one full row-panel's x-blocks run consecutively on
// ONE XCD -> A panel fetched once into that L2) and the row index is dealt
// round-robin across XCDs: row = (s/nx)*8 + xcd (so cheap/dead rows spread
// evenly -> no XCD finishes early). Bijective when (nx*ny*nz) % (8*nx) == 0.
__device__ __forceinline__ int3 swzr(int nx, int ny, int ntot) {
  const int lin = ((int)blockIdx.z * ny + (int)blockIdx.y) * nx + (int)blockIdx.x;
  const int xcd = lin & 7, s = lin >> 3;
  const int row = (s / nx) * 8 + xcd;
  int3 r;
  r.x = s % nx;
  r.y = row % ny;
  r.z = row / ny;
  return r;
}
// stage two 16B chunks of a 128x32 tile (c0=tid, c1=tid+256)
__device__ __forceinline__ void stage2(u16* s, const u16* g, int K, int base,
                                       int c0, int c1, int k0) {
  gld16(s + c0 * 8, g + (size_t)(base + (c0 >> 2)) * K + k0 + (c0 & 3) * 8);
  gld16(s + c1 * 8, g + (size_t)(base + (c1 >> 2)) * K + k0 + (c1 & 3) * 8);
}
// stage one 16B chunk of a 64x32 tile (c=tid in 0..255)
__device__ __forceinline__ void stage1(u16* s, const u16* g, int K, int base,
                                       int c, int k0) {
  gld16(s + c * 8, g + (size_t)(base + (c >> 2)) * K + k0 + (c & 3) * 8);
}
template <typename V>
__device__ __forceinline__ void fragN(V* f, const u16* s, int wo, int fr, int fk, int n) {
  for (int i = 0; i < n; i++) f[i] = *(const V*)(s + (wo + i * 16 + fr) * 32 + fk);
}

// ============ hp dual GEMM: gated = sigmoid(A@Wr) * (A@Wv), tile 128x64 ======
// Writes gated hi/lo (bf16 pair, for exact routing dots) + g16 (fp16, Wo GEMM A).
__global__ __launch_bounds__(256) void gemm_rv(
    const u16* __restrict__ Ahi, const u16* __restrict__ Alo,
    const u16* __restrict__ Brh, const u16* __restrict__ Brl,
    const u16* __restrict__ Bvh, const u16* __restrict__ Bvl,
    int K, int NC, u16* __restrict__ Ghi, u16* __restrict__ Glo,
    u16* __restrict__ G16) {
  __shared__ __align__(16) u16 sAh[4096], sAl[4096];
  __shared__ __align__(16) u16 sRh[2048], sRl[2048], sVh[2048], sVl[2048];
  const int3 b = swzr(16, 64, 1024);
  const int tid = threadIdx.x, lane = tid & 63, wave = tid >> 6;
  const int rowbase = b.y * 128, colbase = b.x * 64;
  const int wm = (wave >> 1) * 64, wn = (wave & 1) * 32;
  floatx4 ar[4][2] = {}, av[4][2] = {};
  const int c0 = tid, c1 = tid + 256;
  for (int k0 = 0; k0 < K; k0 += 32) {
    __syncthreads();
    stage2(sAh, Ahi, K, rowbase, c0, c1, k0);
    stage2(sAl, Alo, K, rowbase, c0, c1, k0);
    stage1(sRh, Brh, K, colbase, c0, k0);
    stage1(sRl, Brl, K, colbase, c0, k0);
    stage1(sVh, Bvh, K, colbase, c0, k0);
    stage1(sVl, Bvl, K, colbase, c0, k0);
    __syncthreads();
    const int fr = lane & 15, fk = (lane >> 4) * 8;
    short8 ah[4], al[4], rh[2], rl[2], vh[2], vl[2];
    fragN(ah, sAh, wm, fr, fk, 4); fragN(al, sAl, wm, fr, fk, 4);
    fragN(rh, sRh, wn, fr, fk, 2); fragN(rl, sRl, wn, fr, fk, 2);
    fragN(vh, sVh, wn, fr, fk, 2); fragN(vl, sVl, wn, fr, fk, 2);
#pragma unroll
    for (int mi = 0; mi < 4; mi++)
#pragma unroll
      for (int ni = 0; ni < 2; ni++) {
        ar[mi][ni] = mf(ah[mi], rh[ni], ar[mi][ni]);
        ar[mi][ni] = mf(ah[mi], rl[ni], ar[mi][ni]);
        ar[mi][ni] = mf(al[mi], rh[ni], ar[mi][ni]);
        av[mi][ni] = mf(ah[mi], vh[ni], av[mi][ni]);
        av[mi][ni] = mf(ah[mi], vl[ni], av[mi][ni]);
        av[mi][ni] = mf(al[mi], vh[ni], av[mi][ni]);
      }
  }
  const int col0 = lane & 15, row0 = (lane >> 4) * 4;
#pragma unroll
  for (int mi = 0; mi < 4; mi++)
#pragma unroll
    for (int ni = 0; ni < 2; ni++)
#pragma unroll
      for (int r = 0; r < 4; r++) {
        const int row = rowbase + wm + mi * 16 + row0 + r;
        const int col = colbase + wn + ni * 16 + col0;
        const size_t idx = (size_t)row * NC + col;
        const float g = sigf(ar[mi][ni][r]) * av[mi][ni][r];
        const u16 h = f2b(g);
        Ghi[idx] = h;
        Glo[idx] = f2b(g - b2f(h));
        G16[idx] = f2h(g);
      }
}

// ============ fp16 GEMM: Xnew = Xin(fp32) + A@Wo, tile 128x64, BK=64 =========
__global__ __launch_bounds__(256) void gemm_wo_f16(
    const u16* __restrict__ A, const u16* __restrict__ BT, int K, int NC,
    const float* __restrict__ Xin, float* __restrict__ Xnew) {
  __shared__ __align__(16) u16 sA0[4096], sA1[4096], sB0[2048], sB1[2048];
  const int3 b = swzr(16, 64, 1024);
  const int tid = threadIdx.x, lane = tid & 63, wave = tid >> 6;
  const int rowbase = b.y * 128, colbase = b.x * 64;
  const int wm = (wave >> 1) * 64, wn = (wave & 1) * 32;
  floatx4 acc[4][2] = {};
  const int c0 = tid, c1 = tid + 256;
  for (int k0 = 0; k0 < K; k0 += 64) {
    __syncthreads();
    stage2(sA0, A, K, rowbase, c0, c1, k0);
    stage2(sA1, A, K, rowbase, c0, c1, k0 + 32);
    stage1(sB0, BT, K, colbase, c0, k0);
    stage1(sB1, BT, K, colbase, c0, k0 + 32);
    __syncthreads();
    const int fr = lane & 15, fk = (lane >> 4) * 8;
    half8 af[4], bf[2];
    fragN(af, sA0, wm, fr, fk, 4);
    fragN(bf, sB0, wn, fr, fk, 2);
#pragma unroll
    for (int mi = 0; mi < 4; mi++)
#pragma unroll
      for (int ni = 0; ni < 2; ni++)
        acc[mi][ni] = mfh(af[mi], bf[ni], acc[mi][ni]);
    fragN(af, sA1, wm, fr, fk, 4);
    fragN(bf, sB1, wn, fr, fk, 2);
#pragma unroll
    for (int mi = 0; mi < 4; mi++)
#pragma unroll
      for (int ni = 0; ni < 2; ni++)
        acc[mi][ni] = mfh(af[mi], bf[ni], acc[mi][ni]);
  }
  const int col0 = lane & 15, row0 = (lane >> 4) * 4;
#pragma unroll
  for (int mi = 0; mi < 4; mi++)
#pragma unroll
    for (int ni = 0; ni < 2; ni++)
#pragma unroll
      for (int r = 0; r < 4; r++) {
        const int row = rowbase + wm + mi * 16 + row0 + r;
        const int col = colbase + wn + ni * 16 + col0;
        const size_t idx = (size_t)row * NC + col;
        Xnew[idx] = Xin[idx] + acc[mi][ni][r];
      }
}

// ============ merged mid expert GEMMs, one launch ============================
// z=0,1: hr_e = relu(h@K_e)^2, tile 128x128, K=C (gathered rows).
// z=2:   tg = (h@W1)*sigmoid(xln@MT), tile 128x64 (x<16), K=C (gathered rows).
__global__ __launch_bounds__(256) void expert_mid(
    const u16* __restrict__ hb, const u16* __restrict__ xlnh,
    const int* __restrict__ idx,
    const u16* __restrict__ KT0p, const u16* __restrict__ KT1p,
    const u16* __restrict__ W1T, const u16* __restrict__ MTp,
    const int* __restrict__ counts, int base,
    u16* __restrict__ hr0, u16* __restrict__ hr1, u16* __restrict__ tg) {
  __shared__ __align__(16) u16 smem[12288];  // 24 KiB, partitioned per path
  const int3 b = swzr(32, 32, 3072);
  const int z = b.z;
  const int tid = threadIdx.x, lane = tid & 63, wave = tid >> 6;
  const int rowbase = b.y * 128;
  const int c0 = tid, c1 = tid + 256;
  const int fr = lane & 15, fk = (lane >> 4) * 8;
  const int col0 = lane & 15, row00 = (lane >> 4) * 4;
  if (z < 2) {
    const int cnt = counts[z] - base;
    if (rowbase >= cnt) return;
    const u16* BT = z ? KT1p : KT0p;
    const int* idxA = idx + z * N_TOK + base;
    u16* Cout = z ? hr1 : hr0;
    u16* sA = smem;          // 128x32
    u16* sB = smem + 4096;   // 128x32
    const int colbase = b.x * 128;
    const int wm = (wave >> 1) * 64, wn = (wave & 1) * 64;
    floatx4 acc[4][4] = {};
    const int g0 = idxA[rowbase + (c0 >> 2)], g1 = idxA[rowbase + (c1 >> 2)];
    const u16* pA0 = hb + (size_t)g0 * C_DIM + (c0 & 3) * 8;
    const u16* pA1 = hb + (size_t)g1 * C_DIM + (c1 & 3) * 8;
    const u16* pB0 = BT + (size_t)(colbase + (c0 >> 2)) * C_DIM + (c0 & 3) * 8;
    const u16* pB1 = BT + (size_t)(colbase + (c1 >> 2)) * C_DIM + (c1 & 3) * 8;
    for (int k0 = 0; k0 < C_DIM; k0 += 32) {
      __syncthreads();
      gld16(sA + c0 * 8, pA0 + k0);
      gld16(sA + c1 * 8, pA1 + k0);
      gld16(sB + c0 * 8, pB0 + k0);
      gld16(sB + c1 * 8, pB1 + k0);
      __syncthreads();
      short8 af[4], bf[4];
      fragN(af, sA, wm, fr, fk, 4);
      fragN(bf, sB, wn, fr, fk, 4);
#pragma unroll
      for (int mi = 0; mi < 4; mi++)
#pragma unroll
        for (int ni = 0; ni < 4; ni++)
          acc[mi][ni] = mf(af[mi], bf[ni], acc[mi][ni]);
    }
#pragma unroll
    for (int mi = 0; mi < 4; mi++)
#pragma unroll
      for (int ni = 0; ni < 4; ni++)
#pragma unroll
        for (int r = 0; r < 4; r++) {
          const int row = rowbase + wm + mi * 16 + row00 + r;
          const int col = colbase + wn + ni * 16 + col0;
          const float v = acc[mi][ni][r];
          const float t = v > 0.f ? v * v : 0.f;
          Cout[(size_t)row * H_DIM + col] = f2b(t);
        }
  } else {
    if (b.x >= 16) return;
    const int cnt = counts[2] - base;
    if (rowbase >= cnt) return;
    const int* idxA = idx + 2 * N_TOK + base;
    u16* s1 = smem;           // 128x32
    u16* s2 = smem + 4096;    // 128x32
    u16* sB1 = smem + 8192;   // 64x32
    u16* sB2 = smem + 10240;  // 64x32
    const int colbase = b.x * 64;
    const int wm = (wave >> 1) * 64, wn = (wave & 1) * 32;
    floatx4 a1[4][2] = {}, a2[4][2] = {};
    const int g0 = idxA[rowbase + (c0 >> 2)], g1 = idxA[rowbase + (c1 >> 2)];
    const u16* p10 = hb + (size_t)g0 * C_DIM + (c0 & 3) * 8;
    const u16* p11 = hb + (size_t)g1 * C_DIM + (c1 & 3) * 8;
    const u16* p20 = xlnh + (size_t)g0 * C_DIM + (c0 & 3) * 8;
    const u16* p21 = xlnh + (size_t)g1 * C_DIM + (c1 & 3) * 8;
    for (int k0 = 0; k0 < C_DIM; k0 += 32) {
      __syncthreads();
      gld16(s1 + c0 * 8, p10 + k0);
      gld16(s1 + c1 * 8, p11 + k0);
      gld16(s2 + c0 * 8, p20 + k0);
      gld16(s2 + c1 * 8, p21 + k0);
      stage1(sB1, W1T, C_DIM, colbase, c0, k0);
      stage1(sB2, MTp, C_DIM, colbase, c0, k0);
      __syncthreads();
      short8 f1[4], f2[4], b1[2], b2[2];
      fragN(f1, s1, wm, fr, fk, 4); fragN(f2, s2, wm, fr, fk, 4);
      fragN(b1, sB1, wn, fr, fk, 2); fragN(b2, sB2, wn, fr, fk, 2);
#pragma unroll
      for (int mi = 0; mi < 4; mi++)
#pragma unroll
        for (int ni = 0; ni < 2; ni++) {
          a1[mi][ni] = mf(f1[mi], b1[ni], a1[mi][ni]);
          a2[mi][ni] = mf(f2[mi], b2[ni], a2[mi][ni]);
        }
    }
#pragma unroll
    for (int mi = 0; mi < 4; mi++)
#pragma unroll
      for (int ni = 0; ni < 2; ni++)
#pragma unroll
        for (int r = 0; r < 4; r++) {
          const int row = rowbase + wm + mi * 16 + row00 + r;
          const int col = colbase + wn + ni * 16 + col0;
          tg[(size_t)(base + row) * C_DIM + col] =
              f2b(a1[mi][ni][r] * sigf(a2[mi][ni][r]));
        }
  }
}

// ============ merged out GEMMs: out = x_new + (A@B)*scale, 128x64, BK=64 =====
// z=0,1: A=hr_e (chunk-local rows), B=V_e, K=H.  z=2: A=tg (base+row), B=W3, K=C.
__global__ __launch_bounds__(256) void vgemm3(
    const u16* __restrict__ hr0, const u16* __restrict__ hr1,
    const u16* __restrict__ tg,
    const u16* __restrict__ VT0p, const u16* __restrict__ VT1p,
    const u16* __restrict__ W3T,
    const int* __restrict__ counts, int base, const int* __restrict__ idx,
    const float* __restrict__ x_new, const float* __restrict__ scalep,
    float* __restrict__ out) {
  const int3 b = swzr(16, 32, 1536);
  const int z = b.z;
  const int cnt = counts[z] - base;
  const int rowbase = b.y * 128;
  if (rowbase >= cnt) return;
  const u16* A; const u16* BT; int K; int arow;
  if (z == 0)      { A = hr0; BT = VT0p; K = H_DIM; arow = rowbase; }
  else if (z == 1) { A = hr1; BT = VT1p; K = H_DIM; arow = rowbase; }
  else             { A = tg;  BT = W3T;  K = C_DIM; arow = base + rowbase; }
  const int* idxO = idx + z * N_TOK + base;
  __shared__ __align__(16) u16 sA0[4096], sA1[4096], sB0[2048], sB1[2048];
  const int tid = threadIdx.x, lane = tid & 63, wave = tid >> 6;
  const int colbase = b.x * 64;
  const int wm = (wave >> 1) * 64, wn = (wave & 1) * 32;
  floatx4 acc[4][2] = {};
  const int c0 = tid, c1 = tid + 256;
  for (int k0 = 0; k0 < K; k0 += 64) {
    __syncthreads();
    stage2(sA0, A, K, arow, c0, c1, k0);
    stage2(sA1, A, K, arow, c0, c1, k0 + 32);
    stage1(sB0, BT, K, colbase, c0, k0);
    stage1(sB1, BT, K, colbase, c0, k0 + 32);
    __syncthreads();
    const int fr = lane & 15, fk = (lane >> 4) * 8;
    short8 af[4], bf[2];
    fragN(af, sA0, wm, fr, fk, 4);
    fragN(bf, sB0, wn, fr, fk, 2);
#pragma unroll
    for (int mi = 0; mi < 4; mi++)
#pragma unroll
      for (int ni = 0; ni < 2; ni++)
        acc[mi][ni] = mf(af[mi], bf[ni], acc[mi][ni]);
    fragN(af, sA1, wm, fr, fk, 4);
    fragN(bf, sB1, wn, fr, fk, 2);
#pragma unroll
    for (int mi = 0; mi < 4; mi++)
#pragma unroll
      for (int ni = 0; ni < 2; ni++)
        acc[mi][ni] = mf(af[mi], bf[ni], acc[mi][ni]);
  }
  const int col0 = lane & 15, row0 = (lane >> 4) * 4;
#pragma unroll
  for (int mi = 0; mi < 4; mi++)
#pragma unroll
    for (int ni = 0; ni < 2; ni++)
#pragma unroll
      for (int r = 0; r < 4; r++) {
        const int row = rowbase + wm + mi * 16 + row0 + r;
        if (row < cnt) {
          const int col = colbase + wn + ni * 16 + col0;
          const int g = idxO[row];
          const size_t o = (size_t)g * C_DIM + col;
          out[o] = x_new[o] + acc[mi][ni][r] * scalep[g];
        }
      }
}

// ============ plain bf16 GEMM, tile 128x128 (MT = W2T @ Wsb prep) ============
template <int EPI>
__global__ __launch_bounds__(256) void ggemm(
    const u16* __restrict__ A, const int* __restrict__ idxA,
    const u16* __restrict__ BT, int K, int NC,
    const int* __restrict__ cntp, int base,
    u16* __restrict__ Cout,
    const float* __restrict__ x_new, const float* __restrict__ scalep,
    const int* __restrict__ idxO, float* __restrict__ out) {
  const int cnt = cntp ? (*cntp - base) : (int)(gridDim.y * 128);
  if ((int)blockIdx.y * 128 >= cnt) return;
  __shared__ __align__(16) u16 sA[4096], sB[4096];
  const int tid = threadIdx.x, lane = tid & 63, wave = tid >> 6;
  const int rowbase = blockIdx.y * 128, colbase = blockIdx.x * 128;
  const int wm = (wave >> 1) * 64, wn = (wave & 1) * 64;
  floatx4 acc[4][4] = {};
  const int c0 = tid, c1 = tid + 256;
  const int r0 = rowbase + (c0 >> 2), r1 = rowbase + (c1 >> 2);
  const int g0 = idxA ? idxA[base + r0] : r0;
  const int g1 = idxA ? idxA[base + r1] : r1;
  const u16* pA0 = A + (size_t)g0 * K + (c0 & 3) * 8;
  const u16* pA1 = A + (size_t)g1 * K + (c1 & 3) * 8;
  const u16* pB0 = BT + (size_t)(colbase + (c0 >> 2)) * K + (c0 & 3) * 8;
  const u16* pB1 = BT + (size_t)(colbase + (c1 >> 2)) * K + (c1 & 3) * 8;
  for (int k0 = 0; k0 < K; k0 += 32) {
    __syncthreads();
    gld16(sA + c0 * 8, pA0 + k0);
    gld16(sA + c1 * 8, pA1 + k0);
    gld16(sB + c0 * 8, pB0 + k0);
    gld16(sB + c1 * 8, pB1 + k0);
    __syncthreads();
    const int fr = lane & 15, fk = (lane >> 4) * 8;
    short8 af[4], bf[4];
    fragN(af, sA, wm, fr, fk, 4);
    fragN(bf, sB, wn, fr, fk, 4);
#pragma unroll
    for (int mi = 0; mi < 4; mi++)
#pragma unroll
      for (int ni = 0; ni < 4; ni++)
        acc[mi][ni] = mf(af[mi], bf[ni], acc[mi][ni]);
  }
  const int col0 = lane & 15, row00 = (lane >> 4) * 4;
#pragma unroll
  for (int mi = 0; mi < 4; mi++)
#pragma unroll
    for (int ni = 0; ni < 4; ni++)
#pragma unroll
      for (int r = 0; r < 4; r++) {
        const int row = rowbase + wm + mi * 16 + row00 + r;
        const int col = colbase + wn + ni * 16 + col0;
        const float v = acc[mi][ni][r];
        if constexpr (EPI == 0) {
          Cout[(size_t)row * NC + col] = f2b(v);
        } else if constexpr (EPI == 2) {
          const float t = v > 0.f ? v * v : 0.f;
          Cout[(size_t)row * NC + col] = f2b(t);
        } else {
          if (row < cnt) {
            const int g = idxO[base + row];
            const size_t o = (size_t)g * NC + col;
            out[o] = x_new[o] + v * scalep[g];
          }
        }
      }
}

// ============ batched C×C weight transposes (z picks matrix) =================
// z: 0=Wr(bf16 hi/lo) 1=Wv(bf16 hi/lo) 2=Wo(fp16) 3=W1 4=W2 5=W3 (bf16 hi)
struct CCBatchArgs {
  const float *Wr, *Wv, *Wo, *W1, *W2, *W3;
  u16 *WrTh, *WrTl, *WvTh, *WvTl, *WoT16, *W1T, *W2T, *W3T;
};
__global__ __launch_bounds__(256) void transpose_cc_batch(CCBatchArgs a) {
  __shared__ float tile[32][33];
  const int z = blockIdx.z;
  const float* in; u16* oh; u16* ol = nullptr; int mode;  // 0 hi,1 hi+lo,2 f16
  switch (z) {
    case 0: in = a.Wr; oh = a.WrTh; ol = a.WrTl; mode = 1; break;
    case 1: in = a.Wv; oh = a.WvTh; ol = a.WvTl; mode = 1; break;
    case 2: in = a.Wo; oh = a.WoT16; mode = 2; break;
    case 3: in = a.W1; oh = a.W1T; mode = 0; break;
    case 4: in = a.W2; oh = a.W2T; mode = 0; break;
    default: in = a.W3; oh = a.W3T; mode = 0; break;
  }
  const int tx = threadIdx.x & 31, ty = threadIdx.x >> 5;
  const int bx = blockIdx.x * 32, by = blockIdx.y * 32;
#pragma unroll
  for (int i = 0; i < 32; i += 8)
    tile[ty + i][tx] = in[(size_t)(by + ty + i) * C_DIM + bx + tx];
  __syncthreads();
#pragma unroll
  for (int i = 0; i < 32; i += 8) {
    const float v = tile[tx][ty + i];
    const size_t o = (size_t)(bx + ty + i) * C_DIM + by + tx;
    if (mode == 2) {
      oh[o] = f2h(v);
    } else {
      const u16 h = f2b(v);
      oh[o] = h;
      if (mode == 1) ol[o] = f2b(v - b2f(h));
    }
  }
}

// ============ batched K/V expert transposes (z picks expert) =================
__global__ __launch_bounds__(256) void transpose_kv(
    const float* __restrict__ in, u16* __restrict__ o0, u16* __restrict__ o1,
    int R, int Cc) {
  __shared__ float tile[32][33];
  const float* ip = in + (size_t)blockIdx.z * R * Cc;
  u16* oh = blockIdx.z ? o1 : o0;
  const int tx = threadIdx.x & 31, ty = threadIdx.x >> 5;
  const int bx = blockIdx.x * 32, by = blockIdx.y * 32;
#pragma unroll
  for (int i = 0; i < 32; i += 8)
    tile[ty + i][tx] = ip[(size_t)(by + ty + i) * Cc + bx + tx];
  __syncthreads();
#pragma unroll
  for (int i = 0; i < 32; i += 8)
    oh[(size_t)(bx + ty + i) * R + by + tx] = f2b(tile[tx][ty + i]);
}

// ============ fp32 -> bf16 straight cast =====================================
__global__ __launch_bounds__(256) void cast_kernel(const float* __restrict__ in,
                                                   u16* __restrict__ o, int n) {
  const int i = blockIdx.x * 256 + threadIdx.x;
  if (i < n) o[i] = f2b(in[i]);
}

// ============ LayerNorm fp32 -> bf16 hi + lo (LN1) ===========================
__global__ __launch_bounds__(256) void ln_kernel(
    const float* __restrict__ x, const float* __restrict__ w,
    const float* __restrict__ b, u16* __restrict__ oh, u16* __restrict__ ol) {
  const int row = blockIdx.x, tid = threadIdx.x;
  const float* xr = x + (size_t)row * C_DIM;
  float vals[4], s = 0.f, ss = 0.f;
#pragma unroll
  for (int i = 0; i < 4; i++) {
    const float t = xr[tid + i * 256];
    vals[i] = t; s += t; ss += t * t;
  }
  for (int off = 32; off; off >>= 1) {
    s += __shfl_xor(s, off, 64);
    ss += __shfl_xor(ss, off, 64);
  }
  __shared__ float red[8];
  const int lane = tid & 63, wave = tid >> 6;
  if (lane == 0) { red[wave] = s; red[4 + wave] = ss; }
  __syncthreads();
  const float S = red[0] + red[1] + red[2] + red[3];
  const float SS = red[4] + red[5] + red[6] + red[7];
  const float mean = S * (1.f / C_DIM);
  const float var = SS * (1.f / C_DIM) - mean * mean;
  const float inv = rsqrtf(var + 1e-5f);
#pragma unroll
  for (int i = 0; i < 4; i++) {
    const int c = tid + i * 256;
    const float y = (vals[i] - mean) * inv * w[c] + b[c];
    const u16 h = f2b(y);
    oh[(size_t)row * C_DIM + c] = h;
    ol[(size_t)row * C_DIM + c] = f2b(y - b2f(h));
  }
}

// ============ prep: p_j = ln2w * w_j ; g_j = sum(p_j) ; b_j = sum(ln2b*w_j) ==
__global__ __launch_bounds__(256) void prep_vec(
    const float* __restrict__ ln2w, const float* __restrict__ ln2b,
    const float* __restrict__ conf_rwkv, const float* __restrict__ conf_trans,
    const float* __restrict__ w_diff, const float* __restrict__ W_aff,
    float* __restrict__ p, float* __restrict__ sg, float* __restrict__ sb) {
  const int j = blockIdx.x, tid = threadIdx.x;
  float gs = 0.f, bs = 0.f;
#pragma unroll
  for (int i = 0; i < 4; i++) {
    const int c = tid + i * 256;
    float wv;
    if (j == 0) wv = conf_rwkv[c];
    else if (j == 1) wv = conf_rwkv[C_DIM + c];
    else if (j == 2) wv = conf_trans[c];
    else if (j == 3) wv = w_diff[c];
    else wv = W_aff[c * 3 + (j - 4)];
    const float pv = ln2w[c] * wv;
    p[j * C_DIM + c] = pv;
    gs += pv;
    bs += ln2b[c] * wv;
  }
  for (int off = 32; off; off >>= 1) {
    gs += __shfl_xor(gs, off, 64);
    bs += __shfl_xor(bs, off, 64);
  }
  __shared__ float red[8];
  const int lane = tid & 63, wave = tid >> 6;
  if (lane == 0) { red[wave] = gs; red[4 + wave] = bs; }
  __syncthreads();
  if (tid == 0) {
    sg[j] = red[0] + red[1] + red[2] + red[3];
    sb[j] = red[4] + red[5] + red[6] + red[7];
  }
}

// ============ u_j = Wo @ p_j  (fp32 GEMV, one wave per output element) =======
__global__ __launch_bounds__(256) void ugemv(
    const float* __restrict__ Wo, const float* __restrict__ p,
    float* __restrict__ u) {
  const int o = blockIdx.x * 4 + (threadIdx.x >> 6);
  const int lane = threadIdx.x & 63;
  const int j = o >> 10, k = o & 1023;
  float s = 0.f;
#pragma unroll
  for (int i = 0; i < 16; i++) {
    const int c = lane + i * 64;
    s += Wo[(size_t)k * C_DIM + c] * p[j * C_DIM + c];
  }
  for (int off = 32; off; off >>= 1) s += __shfl_xor(s, off, 64);
  if (lane == 0) u[o] = s;
}

// ============ routing: exact bids via decomposition; emits h (bf16) ==========
// Also zeroes idx+counts (pz) in its first blocks, replacing zero_kernel.
__global__ __launch_bounds__(256) void route_kernel(
    const float* __restrict__ x, const float* __restrict__ xn,
    const u16* __restrict__ ghi, const u16* __restrict__ glo,
    const float* __restrict__ p, const float* __restrict__ u,
    const float* __restrict__ sg, const float* __restrict__ sb,
    const float* __restrict__ ln2w, const float* __restrict__ ln2b,
    const float* __restrict__ capital,
    int* __restrict__ winner, float* __restrict__ scale, u16* __restrict__ oh,
    int* __restrict__ pz, int nz) {
  {
    const int i = blockIdx.x * 256 + threadIdx.x;
    if (i < nz) pz[i] = 0;
  }
  const int token = blockIdx.x * 4 + (threadIdx.x >> 6);
  const int lane = threadIdx.x & 63;
  const float* xnr = xn + (size_t)token * C_DIM;
  float xv[16], s = 0.f, ss = 0.f;
#pragma unroll
  for (int i = 0; i < 16; i++) {
    const float t = xnr[lane + i * 64];
    xv[i] = t; s += t; ss += t * t;
  }
  for (int off = 32; off; off >>= 1) {
    s += __shfl_xor(s, off, 64);
    ss += __shfl_xor(ss, off, 64);
  }
  const float mean = s * (1.f / C_DIM);
  const float var = ss * (1.f / C_DIM) - mean * mean;
  const float inv = rsqrtf(var + 1e-5f);
  float acc[7] = {};
#pragma unroll
  for (int i = 0; i < 16; i++) {
    const int c = lane + i * 64;
    // h output for experts
    oh[(size_t)token * C_DIM + c] = f2b((xv[i] - mean) * inv * ln2w[c] + ln2b[c]);
    const float xc = x[(size_t)token * C_DIM + c];
    const float gc = b2f(ghi[(size_t)token * C_DIM + c]) +
                     b2f(glo[(size_t)token * C_DIM + c]);
#pragma unroll
    for (int j = 0; j < 7; j++)
      acc[j] += xc * p[j * C_DIM + c] + gc * u[j * C_DIM + c];
  }
  for (int off = 32; off; off >>= 1)
#pragma unroll
    for (int j = 0; j < 7; j++) acc[j] += __shfl_xor(acc[j], off, 64);
  if (lane == 0) {
    float hw[7];
#pragma unroll
    for (int j = 0; j < 7; j++) hw[j] = acc[j] * inv - mean * inv * sg[j] + sb[j];
    const float conf[3] = {1.f / (1.f + expf(-hw[0])), 1.f / (1.f + expf(-hw[1])),
                           1.f / (1.f + expf(-hw[2]))};
    const float diff = 1.f / (1.f + expf(-hw[3]));
    int best = 0; float bb = -1e30f;
#pragma unroll
    for (int e = 0; e < 3; e++) {
      const float bid = conf[e] * capital[e] * diff + hw[4 + e];
      if (bid > bb) { bb = bid; best = e; }  // first-max ties = jnp.argmax
    }
    winner[token] = best;
    scale[token] = conf[best] / (conf[best] + 1e-6f);
  }
}

// ============ compaction =====================================================
__global__ __launch_bounds__(256) void compact_kernel(
    const int* __restrict__ winner, int* __restrict__ idx, int* __restrict__ counts) {
  const int t = blockIdx.x * 256 + threadIdx.x;
  const int w = winner[t];
  const int pos = atomicAdd(counts + w, 1);
  idx[w * N_TOK + pos] = t;
}

extern "C" void kernel_launch(void* const* d_in, const int* in_sizes, int n_in,
                              void* d_out, int out_size, void* d_ws, size_t ws_size,
                              hipStream_t stream) {
  const float* x = (const float*)d_in[0];
  const float* capital = (const float*)d_in[2];
  const float* ln1w = (const float*)d_in[3];
  const float* ln1b = (const float*)d_in[4];
  const float* ln2w = (const float*)d_in[5];
  const float* ln2b = (const float*)d_in[6];
  const float* Wr = (const float*)d_in[7];
  const float* Wv = (const float*)d_in[8];
  const float* Wo = (const float*)d_in[9];
  const float* Wsm = (const float*)d_in[10];
  const float* Krwkv = (const float*)d_in[11];   // (2, C, H)
  const float* Vrwkv = (const float*)d_in[12];   // (2, H, C)
  const float* conf_rwkv = (const float*)d_in[13];
  const float* W1 = (const float*)d_in[14];
  const float* W2 = (const float*)d_in[15];
  const float* W3 = (const float*)d_in[16];
  const float* conf_trans = (const float*)d_in[17];
  const float* w_diff = (const float*)d_in[18];
  const float* W_aff = (const float*)d_in[19];
  float* out = (float*)d_out;

  char* ws = (char*)d_ws;
  size_t off = 0;
  auto alloc = [&](size_t bytes) -> char* {
    char* pp = ws + off;
    off += (bytes + 255) & ~(size_t)255;
    return pp;
  };
  const size_t CC = (size_t)C_DIM * C_DIM * 2;   // 2 MiB
  const size_t CH = (size_t)C_DIM * H_DIM * 2;   // 8 MiB
  const size_t NCb = (size_t)N_TOK * C_DIM * 2;  // 16 MiB
  u16* WrTh = (u16*)alloc(CC); u16* WrTl = (u16*)alloc(CC);
  u16* WvTh = (u16*)alloc(CC); u16* WvTl = (u16*)alloc(CC);
  u16* WoT16 = (u16*)alloc(CC);
  u16* W1T = (u16*)alloc(CC);
  u16* W2T = (u16*)alloc(CC);
  u16* W3T = (u16*)alloc(CC);
  u16* Wsb = (u16*)alloc(CC);
  u16* MT  = (u16*)alloc(CC);   // (Ws@W2)^T
  u16* KT0 = (u16*)alloc(CH);
  u16* VT0 = (u16*)alloc(CH);
  u16* KT1 = (u16*)alloc(CH);
  u16* VT1 = (u16*)alloc(CH);
  u16* xlnh = (u16*)alloc(NCb);   // LN1 hi (live through expert_mid)
  u16* xlnl = (u16*)alloc(NCb);   // LN1 lo; reused as hb (h bf16) after rv
  u16* ghi = (u16*)alloc(NCb);    // gated hi; reused as tg after route
  u16* glo = (u16*)alloc(NCb);    // gated lo; +g16 reused as hr0 after route
  u16* g16 = (u16*)alloc(NCb);    // gated fp16 (Wo GEMM A); part of hr0 after
  float* x_new = (float*)alloc((size_t)N_TOK * C_DIM * 4);  // 32 MiB
  u16* hr1 = (u16*)alloc((size_t)4096 * H_DIM * 2);         // 32 MiB: e1 chunk
  u16* hr0 = glo;  // glo(16MiB)+g16(16MiB) contiguous -> e0 chunk [4096][H]
  int* idx = (int*)alloc(3 * N_TOK * 4);   // contiguous with counts (both 256-aligned)
  int* counts = (int*)alloc(256);
  int* winner = (int*)alloc(N_TOK * 4);
  float* scalep = (float*)alloc(N_TOK * 4);
  float* pvec = (float*)alloc(7 * C_DIM * 4);
  float* uvec = (float*)alloc(7 * C_DIM * 4);
  float* sgv = (float*)alloc(256);
  float* sbv = (float*)alloc(256);

  const dim3 blk(256);
  // batched weight prep: 6 CxC transposes in one launch, K/V pairs in one each
  CCBatchArgs ta = {Wr, Wv, Wo, W1, W2, W3,
                    WrTh, WrTl, WvTh, WvTl, WoT16, W1T, W2T, W3T};
  transpose_cc_batch<<<dim3(32, 32, 6), blk, 0, stream>>>(ta);
  transpose_kv<<<dim3(H_DIM / 32, C_DIM / 32, 2), blk, 0, stream>>>(
      Krwkv, KT0, KT1, C_DIM, H_DIM);
  transpose_kv<<<dim3(C_DIM / 32, H_DIM / 32, 2), blk, 0, stream>>>(
      Vrwkv, VT0, VT1, H_DIM, C_DIM);
  cast_kernel<<<(C_DIM * C_DIM) / 256, blk, 0, stream>>>(Wsm, Wsb, C_DIM * C_DIM);
  // MT = W2T @ Wsb  -> (Ws@W2)^T
  ggemm<0><<<dim3(8, 8), blk, 0, stream>>>(W2T, nullptr, Wsb, C_DIM, C_DIM,
      nullptr, 0, MT, nullptr, nullptr, nullptr, nullptr);
  // routing-vector prep
  prep_vec<<<7, blk, 0, stream>>>(ln2w, ln2b, conf_rwkv, conf_trans, w_diff,
                                  W_aff, pvec, sgv, sbv);
  ugemv<<<7 * C_DIM / 4, blk, 0, stream>>>(Wo, pvec, uvec);

  // LN1 (split)
  ln_kernel<<<N_TOK, blk, 0, stream>>>(x, ln1w, ln1b, xlnh, xlnl);

  // gated = sigmoid(xln@Wr) * (xln@Wv)  (hi/lo + fp16), tile 128x64
  gemm_rv<<<dim3(C_DIM / 64, N_TOK / 128), blk, 0, stream>>>(
      xlnh, xlnl, WrTh, WrTl, WvTh, WvTl, C_DIM, C_DIM, ghi, glo, g16);
  // x_new = x + gated @ Wo (fp16 single pass), tile 128x64 BK=64
  gemm_wo_f16<<<dim3(C_DIM / 64, N_TOK / 128), blk, 0, stream>>>(
      g16, WoT16, C_DIM, C_DIM, x, x_new);
  // routing: exact bids + h (bf16 into xlnl-reuse = hb) + zero idx/counts
  u16* hb = xlnl;
  route_kernel<<<N_TOK / 4, blk, 0, stream>>>(x, x_new, ghi, glo, pvec, uvec,
      sgv, sbv, ln2w, ln2b, capital, winner, scalep, hb, idx, 3 * N_TOK + 64);
  compact_kernel<<<N_TOK / 256, blk, 0, stream>>>(winner, idx, counts);

  // ---- all experts, chunked 4096 rows (chunk 1 only on overflow) ----
  u16* tg = ghi;  // ghi free after route
  for (int c = 0; c < 2; c++) {
    const int base = c * 4096;
    // z=0,1: hr_e = relu(h@K_e)^2 (128x128); z=2: tg = (h@W1)*sig(xln@MT)
    expert_mid<<<dim3(H_DIM / 128, 32, 3), blk, 0, stream>>>(
        hb, xlnh, idx, KT0, KT1, W1T, MT, counts, base, hr0, hr1, tg);
    // z=0,1: out = x_new + (hr_e@V_e)*scale; z=2: out = x_new + (tg@W3)*scale
    vgemm3<<<dim3(C_DIM / 64, 32, 3), blk, 0, stream>>>(
        hr0, hr1, tg, VT0, VT1, W3T, counts, base, idx, x_new, scalep, out);
  }
}